// Round 6
// baseline (20955.853 us; speedup 1.0000x reference)
//
#include <hip/hip_runtime.h>
#include <hip/hip_bf16.h>

// Problem constants: B=16, T=512, E=1024, H=512, 3H=1536, E+H=1536.
//
// R6: recurrence on ONE CU PER DIRECTION - h exchanged through LDS, not the
// fabric. R5's floor was ~4 IF round-trips/step (drain->tag->detect->fetch).
// Now: 2 workgroups x 1024 thr (16 waves); wave owns 32 h-cols x 3 gates,
// Wh in 384 VGPRs/lane (the CU register file is the only memory that holds
// 1.57 MB at zero loop cost); h double-buffered in LDS (16x520 bf16, +8 pad);
// one __syncthreads per step. No tags, no sc0sc1, no global h state.

typedef __attribute__((ext_vector_type(8))) short s8v;
typedef __attribute__((ext_vector_type(4))) short s4v;
typedef __attribute__((ext_vector_type(4))) float f4v;
typedef __attribute__((ext_vector_type(4))) unsigned short us4;
typedef unsigned int u32;

// ws layout (bytes)
#define XBF_OFF   0ull          // 8192*1024*2        = 16,777,216
#define WXBF_OFF  16777216ull   // 3072*1024*2        =  6,291,456
#define WHBF_OFF  23068672ull   // 2*1536*512*2       =  3,145,728
#define XG_OFF    26214400ull   // 2*512*1536*16*2    = 50,331,648

static __device__ __forceinline__ short f2bf(float f) {
  __hip_bfloat16 h = __float2bfloat16(f);
  return *reinterpret_cast<short*>(&h);
}
static __device__ __forceinline__ float bf2f(unsigned short u) {
  union { unsigned int i; float f; } x;
  x.i = ((unsigned int)u) << 16;
  return x.f;
}
static __device__ __forceinline__ float sigmoidf_(float x) {
  return 1.0f / (1.0f + __expf(-x));
}
static __device__ __forceinline__ float tanhf_(float x) {
  return 1.0f - 2.0f / (1.0f + __expf(2.0f * x));
}

// ---------------- cast x to bf16 ----------------
__global__ void cast_x(const float* __restrict__ x, short* __restrict__ xb) {
  int i = (blockIdx.x * 256 + threadIdx.x) * 4;
  f4v v = *reinterpret_cast<const f4v*>(x + i);
  s4v o;
#pragma unroll
  for (int j = 0; j < 4; ++j) o[j] = f2bf(v[j]);
  *reinterpret_cast<s4v*>(xb + i) = o;
}

// ---------------- cast/split weights ----------------
__global__ void cast_w(const float* __restrict__ wf, const float* __restrict__ wb,
                       short* __restrict__ wxb, short* __restrict__ whb) {
  int e = blockIdx.x * 256 + threadIdx.x;  // < 1536*1536
  int dir = blockIdx.y;
  const float* w = dir ? wb : wf;
  int n = e / 1536;
  int k = e - n * 1536;
  short v = f2bf(w[e]);
  if (k < 1024)
    wxb[((size_t)(dir * 1536 + n)) * 1024 + k] = v;
  else
    whb[((size_t)(dir * 1536 + n)) * 512 + (k - 1024)] = v;
}

// ---------------- input GEMM: C = Xb @ Wxb^T, scattered to Xg[dir][t][ng][b] ----
__global__ __launch_bounds__(256) void gemm_in(const short* __restrict__ Xb,
                                               const short* __restrict__ Wxb,
                                               short* __restrict__ Xg) {
  __shared__ short As[128 * 72];
  __shared__ short Bs[128 * 72];
  int tid = threadIdx.x;
  int lane = tid & 63;
  int lr = lane & 15, quad = lane >> 4;
  int widx = tid >> 6;
  int wr = widx >> 1, wc = widx & 1;
  int bm = blockIdx.x, bn = blockIdx.y;

  f4v acc[4][4];
#pragma unroll
  for (int a = 0; a < 4; ++a)
#pragma unroll
    for (int b = 0; b < 4; ++b) acc[a][b] = {0.f, 0.f, 0.f, 0.f};

  const short* Arow = Xb + (size_t)bm * 128 * 1024;
  const short* Brow = Wxb + (size_t)bn * 128 * 1024;

  for (int kt = 0; kt < 16; ++kt) {
#pragma unroll
    for (int c = 0; c < 4; ++c) {
      int fl = c * 2048 + tid * 8;
      int row = fl >> 6, col = fl & 63;
      *reinterpret_cast<s8v*>(&As[row * 72 + col]) =
          *reinterpret_cast<const s8v*>(Arow + row * 1024 + kt * 64 + col);
      *reinterpret_cast<s8v*>(&Bs[row * 72 + col]) =
          *reinterpret_cast<const s8v*>(Brow + row * 1024 + kt * 64 + col);
    }
    __syncthreads();
#pragma unroll
    for (int kk = 0; kk < 2; ++kk) {
      s8v af[4], bfv[4];
#pragma unroll
      for (int mi = 0; mi < 4; ++mi)
        af[mi] = *reinterpret_cast<const s8v*>(&As[(wr * 64 + mi * 16 + lr) * 72 + kk * 32 + quad * 8]);
#pragma unroll
      for (int ni = 0; ni < 4; ++ni)
        bfv[ni] = *reinterpret_cast<const s8v*>(&Bs[(wc * 64 + ni * 16 + lr) * 72 + kk * 32 + quad * 8]);
#pragma unroll
      for (int mi = 0; mi < 4; ++mi)
#pragma unroll
        for (int ni = 0; ni < 4; ++ni)
          acc[mi][ni] = __builtin_amdgcn_mfma_f32_16x16x32_bf16(af[mi], bfv[ni], acc[mi][ni], 0, 0, 0);
    }
    __syncthreads();
  }

  int ngbase = bn * 128;
  int dir = (ngbase >= 1536) ? 1 : 0;
  int ng0 = ngbase - dir * 1536;
#pragma unroll
  for (int mi = 0; mi < 4; ++mi) {
#pragma unroll
    for (int ni = 0; ni < 4; ++ni) {
      int colg = ng0 + wc * 64 + ni * 16 + lr;
#pragma unroll
      for (int r = 0; r < 4; ++r) {
        int m = bm * 128 + wr * 64 + mi * 16 + quad * 4 + r;  // m = b*512 + t
        int b = m >> 9, t = m & 511;
        Xg[(((size_t)(dir * 512 + t)) * 1536 + colg) * 16 + b] = f2bf(acc[mi][ni][r]);
      }
    }
  }
}

// ---------------- recurrence: one CU per direction ----------------
// grid=2 (dir), block=1024 (16 waves). Wave w owns h-cols [32w, 32w+32) as two
// 16-col tiles x 3 gates: 6 B-tile sets x 16 k-frags = 384 VGPRs of Wh.
// h frame double-buffered in LDS (rows=batch 16, cols=512, stride 520 shorts);
// one barrier per step. c-state in registers.
__global__ __launch_bounds__(1024, 1) void lstm_rec(
    const short* __restrict__ Whb, const short* __restrict__ Xg,
    const float* __restrict__ bfw, const float* __restrict__ bbw,
    const float* __restrict__ c0f, const float* __restrict__ c0b,
    const float* __restrict__ h0f, const float* __restrict__ h0b,
    float* __restrict__ out) {
  __shared__ short hbuf[2][16 * 520];

  int tid = threadIdx.x;
  int lane = tid & 63;
  int w = tid >> 6;                 // wave 0..15
  int lr = lane & 15, quad = lane >> 4;
  int dir = blockIdx.x;

  // h(0) into LDS buffer 0
  const float* h0 = dir ? h0b : h0f;
  for (int i = tid; i < 16 * 512; i += 1024) {
    int row = i >> 9, col = i & 511;
    hbuf[0][row * 520 + col] = f2bf(h0[col]);
  }

  // Persistent B fragments: Bw[ni][g][kk], n = g*512 + 32w + 16ni + lr
  const short* Whd = Whb + (size_t)dir * 1536 * 512;
  s8v Bw[2][3][16];
#pragma unroll
  for (int ni = 0; ni < 2; ++ni)
#pragma unroll
    for (int g = 0; g < 3; ++g) {
      const short* rp = Whd + (size_t)(g * 512 + 32 * w + 16 * ni + lr) * 512 + quad * 8;
#pragma unroll
      for (int kk = 0; kk < 16; ++kk)
        Bw[ni][g][kk] = *reinterpret_cast<const s8v*>(rp + kk * 32);
    }

  const float* bias = dir ? bbw : bfw;
  const float* c0 = dir ? c0b : c0f;
  float bi[2], bj[2], bo[2];
  float cst[2][4];
#pragma unroll
  for (int ni = 0; ni < 2; ++ni) {
    int col = 32 * w + 16 * ni + lr;
    bi[ni] = bias[col];
    bj[ni] = bias[512 + col];
    bo[ni] = bias[1024 + col];
    float c0v = c0[col];
#pragma unroll
    for (int r = 0; r < 4; ++r) cst[ni][r] = c0v;
  }

  const short* xgbase = Xg + (size_t)dir * 512 * 1536 * 16;

  // Xg prefetch for s=0: xg[ni][g]
  us4 xg[2][3];
  {
    int t0 = dir ? 511 : 0;
    const short* xgp = xgbase + (size_t)t0 * 1536 * 16;
#pragma unroll
    for (int ni = 0; ni < 2; ++ni)
#pragma unroll
      for (int g = 0; g < 3; ++g)
        xg[ni][g] = *reinterpret_cast<const us4*>(
            xgp + (g * 512 + 32 * w + 16 * ni + lr) * 16 + quad * 4);
  }

  __syncthreads();

  for (int s = 0; s < 512; ++s) {
    int t = dir ? (511 - s) : s;
    const short* cur = hbuf[s & 1];
    short* nxt = hbuf[(s + 1) & 1];

    // K-loop: A-frag from LDS (row=lr, cols quad*8 + 32kk, 16B reads), 6 MFMAs each
    f4v acc[2][3];
#pragma unroll
    for (int ni = 0; ni < 2; ++ni)
#pragma unroll
      for (int g = 0; g < 3; ++g) acc[ni][g] = {0.f, 0.f, 0.f, 0.f};

#pragma unroll
    for (int kk = 0; kk < 16; ++kk) {
      s8v av = *reinterpret_cast<const s8v*>(&cur[lr * 520 + quad * 8 + kk * 32]);
#pragma unroll
      for (int ni = 0; ni < 2; ++ni)
#pragma unroll
        for (int g = 0; g < 3; ++g)
          acc[ni][g] = __builtin_amdgcn_mfma_f32_16x16x32_bf16(av, Bw[ni][g][kk], acc[ni][g], 0, 0, 0);
    }

    // Elementwise (C-layout: row=quad*4+r, col=32w+16ni+lr), write h(s+1) to LDS
    float hn[2][4];
#pragma unroll
    for (int ni = 0; ni < 2; ++ni) {
#pragma unroll
      for (int r = 0; r < 4; ++r) {
        float gi = acc[ni][0][r] + bf2f(xg[ni][0][r]) + bi[ni];
        float gj = acc[ni][1][r] + bf2f(xg[ni][1][r]) + bj[ni];
        float go = acc[ni][2][r] + bf2f(xg[ni][2][r]) + bo[ni];
        float ii = sigmoidf_(gi);
        float jt = tanhf_(gj);
        float oo = sigmoidf_(go);
        cst[ni][r] = (1.0f - ii) * cst[ni][r] + ii * jt;
        hn[ni][r] = tanhf_(cst[ni][r]) * oo;
        nxt[(quad * 4 + r) * 520 + 32 * w + 16 * ni + lr] = f2bf(hn[ni][r]);
      }
    }

    // Off-critical-path: Xg prefetch for s+1, then output stores
    if (s < 511) {
      int tn = dir ? (511 - (s + 1)) : (s + 1);
      const short* xgn = xgbase + (size_t)tn * 1536 * 16;
#pragma unroll
      for (int ni = 0; ni < 2; ++ni)
#pragma unroll
        for (int g = 0; g < 3; ++g)
          xg[ni][g] = *reinterpret_cast<const us4*>(
              xgn + (g * 512 + 32 * w + 16 * ni + lr) * 16 + quad * 4);
    }

#pragma unroll
    for (int ni = 0; ni < 2; ++ni)
#pragma unroll
      for (int r = 0; r < 4; ++r)
        out[((size_t)(quad * 4 + r) * 512 + t) * 1024 + dir * 512 + 32 * w + 16 * ni + lr] = hn[ni][r];

    __syncthreads();
  }
}

extern "C" void kernel_launch(void* const* d_in, const int* in_sizes, int n_in,
                              void* d_out, int out_size, void* d_ws, size_t ws_size,
                              hipStream_t stream) {
  const float* x    = (const float*)d_in[0];
  const float* wfw  = (const float*)d_in[1];
  const float* bfw  = (const float*)d_in[2];
  const float* wbw  = (const float*)d_in[3];
  const float* bbw  = (const float*)d_in[4];
  const float* h0f  = (const float*)d_in[5];
  const float* h0b  = (const float*)d_in[6];
  const float* c0f  = (const float*)d_in[7];
  const float* c0b  = (const float*)d_in[8];
  float* out = (float*)d_out;

  unsigned char* ws = (unsigned char*)d_ws;
  short* Xbf  = (short*)(ws + XBF_OFF);
  short* Wxbf = (short*)(ws + WXBF_OFF);
  short* Whbf = (short*)(ws + WHBF_OFF);
  short* Xg   = (short*)(ws + XG_OFF);

  cast_x<<<8192, 256, 0, stream>>>(x, Xbf);
  cast_w<<<dim3(9216, 2), 256, 0, stream>>>(wfw, wbw, Wxbf, Whbf);
  gemm_in<<<dim3(64, 24), 256, 0, stream>>>(Xbf, Wxbf, Xg);
  lstm_rec<<<2, 1024, 0, stream>>>(Whbf, Xg, bfw, bbw, c0f, c0b, h0f, h0b, out);
}

// Round 7
// 2390.724 us; speedup vs baseline: 8.7655x; 8.7655x over previous
//
#include <hip/hip_runtime.h>
#include <hip/hip_bf16.h>

// Problem constants: B=16, T=512, E=1024, H=512, 3H=1536, E+H=1536.
//
// R7: tag-in-data exchange with asm-forced pipelining. R6 failed (VGPR pool
// is 512/SIMD -> 1024-thr block capped waves at 128 VGPRs, Wh spilled).
// Back to R5's 64 blocks x 1 wave, Wh in 192 VGPRs. Sync chain collapsed:
// h stored as u32=(tag<<16)|bf16 (fire-and-forget, no drain, no tag line);
// consumer does one asm block of 32 global_load_dwordx4 sc0sc1 + vmcnt(0)
// (R4's failure was RA chunking 64 atomic loads into serial groups - the
// asm block guarantees all 32 in flight), validates tags, retries. ~2 IF
// RTTs/step instead of R5's ~4.5.

typedef __attribute__((ext_vector_type(8))) short s8v;
typedef __attribute__((ext_vector_type(4))) short s4v;
typedef __attribute__((ext_vector_type(4))) float f4v;
typedef __attribute__((ext_vector_type(4))) unsigned short us4;
typedef __attribute__((ext_vector_type(4))) unsigned int u32x4;
typedef unsigned int u32;

// ws layout (bytes)
#define XBF_OFF   0ull          // 8192*1024*2        = 16,777,216
#define WXBF_OFF  16777216ull   // 3072*1024*2        =  6,291,456
#define WHBF_OFF  23068672ull   // 2*1536*512*2       =  3,145,728
#define XG_OFF    26214400ull   // 2*512*1536*16*2    = 50,331,648
#define HST_OFF   76546048ull   // 2 dirs * 4 slots * 32KB u32 frames = 262,144

static __device__ __forceinline__ short f2bf(float f) {
  __hip_bfloat16 h = __float2bfloat16(f);
  return *reinterpret_cast<short*>(&h);
}
static __device__ __forceinline__ float bf2f(unsigned short u) {
  union { unsigned int i; float f; } x;
  x.i = ((unsigned int)u) << 16;
  return x.f;
}
static __device__ __forceinline__ float sigmoidf_(float x) {
  return 1.0f / (1.0f + __expf(-x));
}
static __device__ __forceinline__ float tanhf_(float x) {
  return 1.0f - 2.0f / (1.0f + __expf(2.0f * x));
}

// ---------------- init: ring slot 0 = h0 tagged step 0 -----------------
__global__ void init_state(const float* __restrict__ h0f, const float* __restrict__ h0b,
                           u32* __restrict__ hst) {
  int i = blockIdx.x * 256 + threadIdx.x;
  if (i < 2 * 16 * 512) {
    int dir = i >> 13;
    int r = i & 8191;       // b*512 + col
    int col = r & 511;
    const float* h0 = dir ? h0b : h0f;
    // tag 0 in high 16, bf16 in low 16
    hst[(size_t)dir * 4 * 8192 + r] = (u32)(unsigned short)f2bf(h0[col]);
  }
}

// ---------------- cast x to bf16 ----------------
__global__ void cast_x(const float* __restrict__ x, short* __restrict__ xb) {
  int i = (blockIdx.x * 256 + threadIdx.x) * 4;
  f4v v = *reinterpret_cast<const f4v*>(x + i);
  s4v o;
#pragma unroll
  for (int j = 0; j < 4; ++j) o[j] = f2bf(v[j]);
  *reinterpret_cast<s4v*>(xb + i) = o;
}

// ---------------- cast/split weights ----------------
__global__ void cast_w(const float* __restrict__ wf, const float* __restrict__ wb,
                       short* __restrict__ wxb, short* __restrict__ whb) {
  int e = blockIdx.x * 256 + threadIdx.x;  // < 1536*1536
  int dir = blockIdx.y;
  const float* w = dir ? wb : wf;
  int n = e / 1536;
  int k = e - n * 1536;
  short v = f2bf(w[e]);
  if (k < 1024)
    wxb[((size_t)(dir * 1536 + n)) * 1024 + k] = v;
  else
    whb[((size_t)(dir * 1536 + n)) * 512 + (k - 1024)] = v;
}

// ---------------- input GEMM: C = Xb @ Wxb^T, scattered to Xg[dir][t][ng][b] ----
__global__ __launch_bounds__(256) void gemm_in(const short* __restrict__ Xb,
                                               const short* __restrict__ Wxb,
                                               short* __restrict__ Xg) {
  __shared__ short As[128 * 72];
  __shared__ short Bs[128 * 72];
  int tid = threadIdx.x;
  int lane = tid & 63;
  int lr = lane & 15, quad = lane >> 4;
  int widx = tid >> 6;
  int wr = widx >> 1, wc = widx & 1;
  int bm = blockIdx.x, bn = blockIdx.y;

  f4v acc[4][4];
#pragma unroll
  for (int a = 0; a < 4; ++a)
#pragma unroll
    for (int b = 0; b < 4; ++b) acc[a][b] = {0.f, 0.f, 0.f, 0.f};

  const short* Arow = Xb + (size_t)bm * 128 * 1024;
  const short* Brow = Wxb + (size_t)bn * 128 * 1024;

  for (int kt = 0; kt < 16; ++kt) {
#pragma unroll
    for (int c = 0; c < 4; ++c) {
      int fl = c * 2048 + tid * 8;
      int row = fl >> 6, col = fl & 63;
      *reinterpret_cast<s8v*>(&As[row * 72 + col]) =
          *reinterpret_cast<const s8v*>(Arow + row * 1024 + kt * 64 + col);
      *reinterpret_cast<s8v*>(&Bs[row * 72 + col]) =
          *reinterpret_cast<const s8v*>(Brow + row * 1024 + kt * 64 + col);
    }
    __syncthreads();
#pragma unroll
    for (int kk = 0; kk < 2; ++kk) {
      s8v af[4], bfv[4];
#pragma unroll
      for (int mi = 0; mi < 4; ++mi)
        af[mi] = *reinterpret_cast<const s8v*>(&As[(wr * 64 + mi * 16 + lr) * 72 + kk * 32 + quad * 8]);
#pragma unroll
      for (int ni = 0; ni < 4; ++ni)
        bfv[ni] = *reinterpret_cast<const s8v*>(&Bs[(wc * 64 + ni * 16 + lr) * 72 + kk * 32 + quad * 8]);
#pragma unroll
      for (int mi = 0; mi < 4; ++mi)
#pragma unroll
        for (int ni = 0; ni < 4; ++ni)
          acc[mi][ni] = __builtin_amdgcn_mfma_f32_16x16x32_bf16(af[mi], bfv[ni], acc[mi][ni], 0, 0, 0);
    }
    __syncthreads();
  }

  int ngbase = bn * 128;
  int dir = (ngbase >= 1536) ? 1 : 0;
  int ng0 = ngbase - dir * 1536;
#pragma unroll
  for (int mi = 0; mi < 4; ++mi) {
#pragma unroll
    for (int ni = 0; ni < 4; ++ni) {
      int colg = ng0 + wc * 64 + ni * 16 + lr;
#pragma unroll
      for (int r = 0; r < 4; ++r) {
        int m = bm * 128 + wr * 64 + mi * 16 + quad * 4 + r;  // m = b*512 + t
        int b = m >> 9, t = m & 511;
        Xg[(((size_t)(dir * 512 + t)) * 1536 + colg) * 16 + b] = f2bf(acc[mi][ni][r]);
      }
    }
  }
}

// ---------------- recurrence ----------------
// 64 blocks x 64 threads (1 wave each); wave wg=blockIdx: dir=wg>>5, slice=wg&31.
// Wave owns h-cols [16*slice,16*slice+16). Wh in 192 VGPRs. h exchanged through
// a 4-slot u32 ring (tag<<16 | bf16) at IF scope (sc0 sc1); fire-and-forget
// publish, self-validating bulk fetch.
__global__ __launch_bounds__(64, 1) void lstm_rec(
    const short* __restrict__ Whb, const short* __restrict__ Xg,
    const float* __restrict__ bfw, const float* __restrict__ bbw,
    const float* __restrict__ c0f, const float* __restrict__ c0b,
    u32* __restrict__ hst, float* __restrict__ out) {
  int lane = threadIdx.x & 63;
  int lr = lane & 15, quad = lane >> 4;
  int wg = blockIdx.x;
  int dir = wg >> 5;
  int slice = wg & 31;
  int col16 = slice * 16;

  // Persistent B fragments (normal cached loads)
  const short* Whd = Whb + (size_t)dir * 1536 * 512;
  s8v Bw[3][16];
#pragma unroll
  for (int g = 0; g < 3; ++g) {
    const short* rp = Whd + (size_t)(g * 512 + col16 + lr) * 512 + quad * 8;
#pragma unroll
    for (int k = 0; k < 16; ++k) Bw[g][k] = *reinterpret_cast<const s8v*>(rp + k * 32);
  }

  const float* bias = dir ? bbw : bfw;
  float bi = bias[col16 + lr];
  float bj = bias[512 + col16 + lr];
  float bo = bias[1024 + col16 + lr];

  const float* c0 = dir ? c0b : c0f;
  float cst[4];
  {
    float c0v = c0[col16 + lr];
#pragma unroll
    for (int r = 0; r < 4; ++r) cst[r] = c0v;
  }

  u32* hring = hst + (size_t)dir * 4 * 8192;  // 4 frames of [16 rows][512 cols] u32
  const short* xgbase = Xg + (size_t)dir * 512 * 1536 * 16;

  // First Xg prefetch (t for s=0)
  int t0 = dir ? 511 : 0;
  const short* xgp = xgbase + (size_t)t0 * 1536 * 16;
  us4 xiv = *reinterpret_cast<const us4*>(xgp + (col16 + lr) * 16 + quad * 4);
  us4 xjv = *reinterpret_cast<const us4*>(xgp + (512 + col16 + lr) * 16 + quad * 4);
  us4 xov = *reinterpret_cast<const us4*>(xgp + (1024 + col16 + lr) * 16 + quad * 4);

  for (int s = 0; s < 512; ++s) {
    int t = dir ? (511 - s) : s;

    // --- acquire h(s): self-validating bulk fetch (retry until tags==s) ---
    // Per lane: row lr, u32 cols quad*8 + 32k + [0,8). 32 dwordx4 in one asm
    // block, single vmcnt(0) -> all in flight, one RTT per pass.
    const char* hp = (const char*)(hring + (size_t)(s & 3) * 8192) + lr * 2048 + quad * 32;
    u32x4 d[32];
    for (;;) {
      asm volatile(
          "global_load_dwordx4 %0, %32, off sc0 sc1\n\t"
          "global_load_dwordx4 %1, %32, off offset:16 sc0 sc1\n\t"
          "global_load_dwordx4 %2, %32, off offset:128 sc0 sc1\n\t"
          "global_load_dwordx4 %3, %32, off offset:144 sc0 sc1\n\t"
          "global_load_dwordx4 %4, %32, off offset:256 sc0 sc1\n\t"
          "global_load_dwordx4 %5, %32, off offset:272 sc0 sc1\n\t"
          "global_load_dwordx4 %6, %32, off offset:384 sc0 sc1\n\t"
          "global_load_dwordx4 %7, %32, off offset:400 sc0 sc1\n\t"
          "global_load_dwordx4 %8, %32, off offset:512 sc0 sc1\n\t"
          "global_load_dwordx4 %9, %32, off offset:528 sc0 sc1\n\t"
          "global_load_dwordx4 %10, %32, off offset:640 sc0 sc1\n\t"
          "global_load_dwordx4 %11, %32, off offset:656 sc0 sc1\n\t"
          "global_load_dwordx4 %12, %32, off offset:768 sc0 sc1\n\t"
          "global_load_dwordx4 %13, %32, off offset:784 sc0 sc1\n\t"
          "global_load_dwordx4 %14, %32, off offset:896 sc0 sc1\n\t"
          "global_load_dwordx4 %15, %32, off offset:912 sc0 sc1\n\t"
          "global_load_dwordx4 %16, %32, off offset:1024 sc0 sc1\n\t"
          "global_load_dwordx4 %17, %32, off offset:1040 sc0 sc1\n\t"
          "global_load_dwordx4 %18, %32, off offset:1152 sc0 sc1\n\t"
          "global_load_dwordx4 %19, %32, off offset:1168 sc0 sc1\n\t"
          "global_load_dwordx4 %20, %32, off offset:1280 sc0 sc1\n\t"
          "global_load_dwordx4 %21, %32, off offset:1296 sc0 sc1\n\t"
          "global_load_dwordx4 %22, %32, off offset:1408 sc0 sc1\n\t"
          "global_load_dwordx4 %23, %32, off offset:1424 sc0 sc1\n\t"
          "global_load_dwordx4 %24, %32, off offset:1536 sc0 sc1\n\t"
          "global_load_dwordx4 %25, %32, off offset:1552 sc0 sc1\n\t"
          "global_load_dwordx4 %26, %32, off offset:1664 sc0 sc1\n\t"
          "global_load_dwordx4 %27, %32, off offset:1680 sc0 sc1\n\t"
          "global_load_dwordx4 %28, %32, off offset:1792 sc0 sc1\n\t"
          "global_load_dwordx4 %29, %32, off offset:1808 sc0 sc1\n\t"
          "global_load_dwordx4 %30, %32, off offset:1920 sc0 sc1\n\t"
          "global_load_dwordx4 %31, %32, off offset:1936 sc0 sc1\n\t"
          "s_waitcnt vmcnt(0)"
          : "=v"(d[0]), "=v"(d[1]), "=v"(d[2]), "=v"(d[3]), "=v"(d[4]),
            "=v"(d[5]), "=v"(d[6]), "=v"(d[7]), "=v"(d[8]), "=v"(d[9]),
            "=v"(d[10]), "=v"(d[11]), "=v"(d[12]), "=v"(d[13]), "=v"(d[14]),
            "=v"(d[15]), "=v"(d[16]), "=v"(d[17]), "=v"(d[18]), "=v"(d[19]),
            "=v"(d[20]), "=v"(d[21]), "=v"(d[22]), "=v"(d[23]), "=v"(d[24]),
            "=v"(d[25]), "=v"(d[26]), "=v"(d[27]), "=v"(d[28]), "=v"(d[29]),
            "=v"(d[30]), "=v"(d[31])
          : "v"(hp)
          : "memory");
      // Each dwordx4 lies in one 64B producer-store transaction -> checking
      // one tag per dwordx4 validates the chunk.
      bool ok = true;
#pragma unroll
      for (int k = 0; k < 32; ++k) ok &= ((d[k][0] >> 16) == (u32)s);
      if (__ballot(ok) == ~0ull) break;
    }

    // --- perm-pack u32 pairs to bf16 fragments, MFMA ---
    f4v a0 = {0.f, 0.f, 0.f, 0.f};
    f4v a1 = {0.f, 0.f, 0.f, 0.f};
    f4v a2 = {0.f, 0.f, 0.f, 0.f};
#pragma unroll
    for (int k = 0; k < 16; ++k) {
      union { u32 u[4]; s8v v; } f;
      f.u[0] = __builtin_amdgcn_perm(d[2 * k][1], d[2 * k][0], 0x05040100u);
      f.u[1] = __builtin_amdgcn_perm(d[2 * k][3], d[2 * k][2], 0x05040100u);
      f.u[2] = __builtin_amdgcn_perm(d[2 * k + 1][1], d[2 * k + 1][0], 0x05040100u);
      f.u[3] = __builtin_amdgcn_perm(d[2 * k + 1][3], d[2 * k + 1][2], 0x05040100u);
      a0 = __builtin_amdgcn_mfma_f32_16x16x32_bf16(f.v, Bw[0][k], a0, 0, 0, 0);
      a1 = __builtin_amdgcn_mfma_f32_16x16x32_bf16(f.v, Bw[1][k], a1, 0, 0, 0);
      a2 = __builtin_amdgcn_mfma_f32_16x16x32_bf16(f.v, Bw[2][k], a2, 0, 0, 0);
    }

    // --- elementwise (C-layout: row=quad*4+r, col=col16+lr) ---
    float hn[4];
    u32 hv[4];
    u32 tagn = (u32)(s + 1) << 16;
#pragma unroll
    for (int r = 0; r < 4; ++r) {
      float gi = a0[r] + bf2f(xiv[r]) + bi;
      float gj = a1[r] + bf2f(xjv[r]) + bj;
      float go = a2[r] + bf2f(xov[r]) + bo;
      float ii = sigmoidf_(gi);
      float jt = tanhf_(gj);
      float oo = sigmoidf_(go);
      cst[r] = (1.0f - ii) * cst[r] + ii * jt;
      hn[r] = tanhf_(cst[r]) * oo;
      hv[r] = tagn | (u32)(unsigned short)f2bf(hn[r]);
    }

    // --- publish h(s+1): 4 fire-and-forget tagged u32 stores (no drain) ---
    {
      u32* fr = hring + (size_t)((s + 1) & 3) * 8192;
      const u32* hb = fr + (quad * 4 + 2) * 512 + col16 + lr;  // base at r=2 row
      asm volatile(
          "global_store_dword %4, %0, off offset:-4096 sc0 sc1\n\t"
          "global_store_dword %4, %1, off offset:-2048 sc0 sc1\n\t"
          "global_store_dword %4, %2, off sc0 sc1\n\t"
          "global_store_dword %4, %3, off offset:2048 sc0 sc1"
          :: "v"(hv[0]), "v"(hv[1]), "v"(hv[2]), "v"(hv[3]), "v"(hb)
          : "memory");
    }

    // --- off-critical-path: output store + next-step Xg prefetch ---
#pragma unroll
    for (int r = 0; r < 4; ++r)
      out[((size_t)(quad * 4 + r) * 512 + t) * 1024 + dir * 512 + col16 + lr] = hn[r];

    if (s < 511) {
      int tn = dir ? (511 - (s + 1)) : (s + 1);
      const short* xgn = xgbase + (size_t)tn * 1536 * 16;
      xiv = *reinterpret_cast<const us4*>(xgn + (col16 + lr) * 16 + quad * 4);
      xjv = *reinterpret_cast<const us4*>(xgn + (512 + col16 + lr) * 16 + quad * 4);
      xov = *reinterpret_cast<const us4*>(xgn + (1024 + col16 + lr) * 16 + quad * 4);
    }
  }
}

extern "C" void kernel_launch(void* const* d_in, const int* in_sizes, int n_in,
                              void* d_out, int out_size, void* d_ws, size_t ws_size,
                              hipStream_t stream) {
  const float* x    = (const float*)d_in[0];
  const float* wfw  = (const float*)d_in[1];
  const float* bfw  = (const float*)d_in[2];
  const float* wbw  = (const float*)d_in[3];
  const float* bbw  = (const float*)d_in[4];
  const float* h0f  = (const float*)d_in[5];
  const float* h0b  = (const float*)d_in[6];
  const float* c0f  = (const float*)d_in[7];
  const float* c0b  = (const float*)d_in[8];
  float* out = (float*)d_out;

  unsigned char* ws = (unsigned char*)d_ws;
  short* Xbf  = (short*)(ws + XBF_OFF);
  short* Wxbf = (short*)(ws + WXBF_OFF);
  short* Whbf = (short*)(ws + WHBF_OFF);
  short* Xg   = (short*)(ws + XG_OFF);
  u32*   hst  = (u32*)(ws + HST_OFF);

  init_state<<<64, 256, 0, stream>>>(h0f, h0b, hst);
  cast_x<<<8192, 256, 0, stream>>>(x, Xbf);
  cast_w<<<dim3(9216, 2), 256, 0, stream>>>(wfw, wbw, Wxbf, Whbf);
  gemm_in<<<dim3(64, 24), 256, 0, stream>>>(Xbf, Wxbf, Xg);
  lstm_rec<<<64, 64, 0, stream>>>(Whbf, Xg, bfw, bbw, c0f, c0b, hst, out);
}